// Round 1
// baseline (224.359 us; speedup 1.0000x reference)
//
#include <hip/hip_runtime.h>
#include <hip/hip_bf16.h>

typedef __attribute__((ext_vector_type(8))) short s16x8;
typedef __attribute__((ext_vector_type(4))) float f32x4;

#define SEQ 2048
#define NB 2
#define NH 16
#define HD 64
#define DIM 1024
#define MR (NB * SEQ)

__device__ __forceinline__ unsigned short f2b(float f) {
    unsigned u = __float_as_uint(f);
    u += 0x7fffu + ((u >> 16) & 1u);
    return (unsigned short)(u >> 16);
}

__global__ void cast_kernel(const float* __restrict__ src, unsigned short* __restrict__ dst, int n4) {
    int i = blockIdx.x * blockDim.x + threadIdx.x;
    if (i >= n4) return;
    float4 v = reinterpret_cast<const float4*>(src)[i];
    ushort4 o;
    o.x = f2b(v.x); o.y = f2b(v.y); o.z = f2b(v.z); o.w = f2b(v.w);
    reinterpret_cast<ushort4*>(dst)[i] = o;
}

__global__ void rope_tab_kernel(float2* __restrict__ tab) {
    int i = blockIdx.x * blockDim.x + threadIdx.x; // 2048*32 = 65536
    int pos = i >> 5, fi = i & 31;
    float freq = expf((float)fi * (-9.210340371976184f / 32.0f)); // 10000^(-fi/32)
    float emb = (float)pos * freq;
    tab[i] = make_float2(cosf(emb), sinf(emb));
}

// C = A * B^T ; A [M][1024] bf16 row-major, Bw [N][1024] bf16 row-major.
// EPI==0: N=3072 fused QKV; epilogue applies RoPE to Q,K; V stored transposed.
// EPI==1: N=1024 output projection; epilogue adds bias, stores fp32.
template <int EPI>
__global__ __launch_bounds__(256) void gemm_bt(
    const unsigned short* __restrict__ A,
    const unsigned short* __restrict__ Bw,
    const float2* __restrict__ tab,
    unsigned short* __restrict__ qw,
    unsigned short* __restrict__ kw,
    unsigned short* __restrict__ vw,
    float* __restrict__ out,
    const float* __restrict__ bias)
{
    __shared__ unsigned short As[128][40]; // BK=32 + pad 8 -> 2-way bank alias (free)
    __shared__ unsigned short Bs[128][40];
    const int t = threadIdx.x;
    const int wid = t >> 6;
    const int lane = t & 63;
    const int wr = wid >> 1, wc = wid & 1;
    const int lo = lane & 15, hi = lane >> 4;
    const int m0 = blockIdx.y * 128, n0 = blockIdx.x * 128;
    const int srow = t >> 2, sk = (t & 3) * 8;

    f32x4 acc[4][4] = {};
    const unsigned short* ap0 = A + (long)(m0 + srow) * DIM + sk;
    const unsigned short* ap1 = A + (long)(m0 + srow + 64) * DIM + sk;
    const unsigned short* bp0 = Bw + (long)(n0 + srow) * DIM + sk;
    const unsigned short* bp1 = Bw + (long)(n0 + srow + 64) * DIM + sk;

    for (int k0 = 0; k0 < DIM; k0 += 32) {
        int4 a0 = *reinterpret_cast<const int4*>(ap0 + k0);
        int4 a1 = *reinterpret_cast<const int4*>(ap1 + k0);
        int4 b0 = *reinterpret_cast<const int4*>(bp0 + k0);
        int4 b1 = *reinterpret_cast<const int4*>(bp1 + k0);
        __syncthreads();
        *reinterpret_cast<int4*>(&As[srow][sk]) = a0;
        *reinterpret_cast<int4*>(&As[srow + 64][sk]) = a1;
        *reinterpret_cast<int4*>(&Bs[srow][sk]) = b0;
        *reinterpret_cast<int4*>(&Bs[srow + 64][sk]) = b1;
        __syncthreads();
        s16x8 af[4], bf[4];
#pragma unroll
        for (int i = 0; i < 4; ++i)
            af[i] = *reinterpret_cast<const s16x8*>(&As[wr * 64 + i * 16 + lo][hi * 8]);
#pragma unroll
        for (int j = 0; j < 4; ++j)
            bf[j] = *reinterpret_cast<const s16x8*>(&Bs[wc * 64 + j * 16 + lo][hi * 8]);
#pragma unroll
        for (int i = 0; i < 4; ++i)
#pragma unroll
            for (int j = 0; j < 4; ++j)
                acc[i][j] = __builtin_amdgcn_mfma_f32_16x16x32_bf16(af[i], bf[j], acc[i][j], 0, 0, 0);
    }

    const int rowb = m0 + wr * 64;
    const int colb = n0 + wc * 64; // 64-aligned -> one head per 64-col span
    if (EPI == 0) {
#pragma unroll
        for (int ai = 0; ai < 4; ++ai) {
#pragma unroll
            for (int cp = 0; cp < 2; ++cp) {
                f32x4 v1 = acc[ai][cp];      // d in [0,32)
                f32x4 v2 = acc[ai][cp + 2];  // d+32
                int e = colb + cp * 16 + lo; // global output feature 0..3071
                int which = e >> 10;         // 0=Q 1=K 2=V
                int eh = e & 1023;
                int h = eh >> 6, d = eh & 63; // d in [0,32)
#pragma unroll
                for (int r = 0; r < 4; ++r) {
                    int m = rowb + ai * 16 + hi * 4 + r;
                    int b = m >> 11, pos = m & (SEQ - 1);
                    long hb = (long)(b * NH + h);
                    if (which == 2) {
                        // V transposed: vw[b,h,d,s]
                        vw[(hb * HD + d) * SEQ + pos] = f2b(v1[r]);
                        vw[(hb * HD + d + 32) * SEQ + pos] = f2b(v2[r]);
                    } else {
                        float2 cs = tab[pos * 32 + d];
                        unsigned short* dst = (which == 0) ? qw : kw;
                        long off = (hb * SEQ + pos) * HD;
                        dst[off + d]      = f2b(v1[r] * cs.x - v2[r] * cs.y);
                        dst[off + d + 32] = f2b(v1[r] * cs.y + v2[r] * cs.x);
                    }
                }
            }
        }
    } else {
#pragma unroll
        for (int ai = 0; ai < 4; ++ai)
#pragma unroll
            for (int cj = 0; cj < 4; ++cj) {
                int n = colb + cj * 16 + lo;
                float bv = bias[n];
#pragma unroll
                for (int r = 0; r < 4; ++r) {
                    int m = rowb + ai * 16 + hi * 4 + r;
                    out[(long)m * DIM + n] = acc[ai][cj][r] + bv;
                }
            }
    }
}

// Flash attention. Grid: (SEQ/64, NB*NH). 4 waves; wave w owns 16 Q-rows.
// qw/kw: [bh][s][64] bf16; vw: [bh][64][s] bf16 (transposed); ao: [b][s][1024] bf16.
__global__ __launch_bounds__(256) void flash_attn(
    const unsigned short* __restrict__ qw,
    const unsigned short* __restrict__ kw,
    const unsigned short* __restrict__ vw,
    unsigned short* __restrict__ ao)
{
    __shared__ unsigned short Qs[64][72];
    __shared__ unsigned short Ks[64][72];
    __shared__ unsigned short Vs[64][72]; // Vs[d][s_local]
    __shared__ unsigned short Ps[4][16][72];
    const int t = threadIdx.x;
    const int wid = t >> 6, lane = t & 63;
    const int lo = lane & 15, hi = lane >> 4;
    const int bh = blockIdx.y;
    const int q0 = blockIdx.x * 64;
    const unsigned short* qh = qw + (long)bh * SEQ * HD;
    const unsigned short* kh = kw + (long)bh * SEQ * HD;
    const unsigned short* vh = vw + (long)bh * HD * SEQ;

    {
        int row = t >> 3, seg = (t & 7) * 8;
        *reinterpret_cast<int4*>(&Qs[row][seg]) = *reinterpret_cast<const int4*>(qh + (long)(q0 + row) * HD + seg);
        *reinterpret_cast<int4*>(&Qs[row + 32][seg]) = *reinterpret_cast<const int4*>(qh + (long)(q0 + row + 32) * HD + seg);
    }
    __syncthreads();
    s16x8 aq[2];
#pragma unroll
    for (int ks = 0; ks < 2; ++ks)
        aq[ks] = *reinterpret_cast<const s16x8*>(&Qs[wid * 16 + lo][ks * 32 + hi * 8]);

    f32x4 od[4] = {};
    float mrun[4], lrun[4];
#pragma unroll
    for (int r = 0; r < 4; ++r) { mrun[r] = -1e30f; lrun[r] = 0.f; }

    for (int kt = 0; kt < SEQ / 64; ++kt) {
        const int kb = kt * 64;
        int row = t >> 3, seg = (t & 7) * 8;
        int4 k0v = *reinterpret_cast<const int4*>(kh + (long)(kb + row) * HD + seg);
        int4 k1v = *reinterpret_cast<const int4*>(kh + (long)(kb + row + 32) * HD + seg);
        int4 v0v = *reinterpret_cast<const int4*>(vh + (long)row * SEQ + kb + seg);
        int4 v1v = *reinterpret_cast<const int4*>(vh + (long)(row + 32) * SEQ + kb + seg);
        __syncthreads(); // previous tile fully consumed
        *reinterpret_cast<int4*>(&Ks[row][seg]) = k0v;
        *reinterpret_cast<int4*>(&Ks[row + 32][seg]) = k1v;
        *reinterpret_cast<int4*>(&Vs[row][seg]) = v0v;
        *reinterpret_cast<int4*>(&Vs[row + 32][seg]) = v1v;
        __syncthreads();

        // S = Q K^T (16x64 per wave)
        f32x4 sc[4] = {};
#pragma unroll
        for (int ks = 0; ks < 2; ++ks)
#pragma unroll
            for (int cj = 0; cj < 4; ++cj) {
                s16x8 bk = *reinterpret_cast<const s16x8*>(&Ks[cj * 16 + lo][ks * 32 + hi * 8]);
                sc[cj] = __builtin_amdgcn_mfma_f32_16x16x32_bf16(aq[ks], bk, sc[cj], 0, 0, 0);
            }

        // online softmax, rows = hi*4 + r (relative to wave's 16-row span)
#pragma unroll
        for (int r = 0; r < 4; ++r) {
            float mx = fmaxf(fmaxf(sc[0][r], sc[1][r]), fmaxf(sc[2][r], sc[3][r])) * 0.125f;
#pragma unroll
            for (int off = 1; off < 16; off <<= 1) mx = fmaxf(mx, __shfl_xor(mx, off));
            float mn = fmaxf(mrun[r], mx);
            float al = __expf(mrun[r] - mn);
            mrun[r] = mn;
            float p[4], rs = 0.f;
#pragma unroll
            for (int cj = 0; cj < 4; ++cj) { p[cj] = __expf(sc[cj][r] * 0.125f - mn); rs += p[cj]; }
#pragma unroll
            for (int off = 1; off < 16; off <<= 1) rs += __shfl_xor(rs, off);
            lrun[r] = lrun[r] * al + rs;
#pragma unroll
            for (int cj = 0; cj < 4; ++cj) od[cj][r] *= al;
            int prow = hi * 4 + r;
#pragma unroll
            for (int cj = 0; cj < 4; ++cj) Ps[wid][prow][cj * 16 + lo] = f2b(p[cj]);
        }

        // O += P * V  (per-wave Ps, no barrier needed)
#pragma unroll
        for (int ks = 0; ks < 2; ++ks) {
            s16x8 ap = *reinterpret_cast<const s16x8*>(&Ps[wid][lo][ks * 32 + hi * 8]);
#pragma unroll
            for (int cj = 0; cj < 4; ++cj) {
                s16x8 bv = *reinterpret_cast<const s16x8*>(&Vs[cj * 16 + lo][ks * 32 + hi * 8]);
                od[cj] = __builtin_amdgcn_mfma_f32_16x16x32_bf16(ap, bv, od[cj], 0, 0, 0);
            }
        }
    }

    const int b = bh >> 4, h = bh & 15;
#pragma unroll
    for (int r = 0; r < 4; ++r) {
        float ool = 1.f / lrun[r];
        int srow = q0 + wid * 16 + hi * 4 + r;
#pragma unroll
        for (int cj = 0; cj < 4; ++cj) {
            int col = h * 64 + cj * 16 + lo;
            ao[((long)(b * SEQ + srow)) * DIM + col] = f2b(od[cj][r] * ool);
        }
    }
}

extern "C" void kernel_launch(void* const* d_in, const int* in_sizes, int n_in,
                              void* d_out, int out_size, void* d_ws, size_t ws_size,
                              hipStream_t stream) {
    const float* x   = (const float*)d_in[0];
    const float* wq  = (const float*)d_in[1];
    const float* wk  = (const float*)d_in[2];
    const float* wv  = (const float*)d_in[3];
    const float* wo  = (const float*)d_in[4];
    const float* wob = (const float*)d_in[5];

    char* ws = (char*)d_ws;
    unsigned short* xb   = (unsigned short*)(ws);             // 8.0 MiB
    unsigned short* wqkv = (unsigned short*)(ws + 8388608);   // 6.0 MiB
    unsigned short* wwo  = (unsigned short*)(ws + 14680064);  // 2.0 MiB
    unsigned short* qw   = (unsigned short*)(ws + 16777216);  // 8.0 MiB
    unsigned short* kw   = (unsigned short*)(ws + 25165824);  // 8.0 MiB
    unsigned short* vw   = (unsigned short*)(ws + 33554432);  // 8.0 MiB
    unsigned short* ao   = (unsigned short*)(ws + 41943040);  // 8.0 MiB
    float2* tab          = (float2*)(ws + 50331648);          // 512 KiB

    cast_kernel<<<4096, 256, 0, stream>>>(x, xb, MR * DIM / 4);
    cast_kernel<<<1024, 256, 0, stream>>>(wq, wqkv, DIM * DIM / 4);
    cast_kernel<<<1024, 256, 0, stream>>>(wk, wqkv + DIM * DIM, DIM * DIM / 4);
    cast_kernel<<<1024, 256, 0, stream>>>(wv, wqkv + 2 * DIM * DIM, DIM * DIM / 4);
    cast_kernel<<<1024, 256, 0, stream>>>(wo, wwo, DIM * DIM / 4);
    rope_tab_kernel<<<256, 256, 0, stream>>>(tab);

    gemm_bt<0><<<dim3(24, 32), 256, 0, stream>>>(xb, wqkv, tab, qw, kw, vw, nullptr, nullptr);
    flash_attn<<<dim3(32, 32), 256, 0, stream>>>(qw, kw, vw, ao);
    gemm_bt<1><<<dim3(8, 32), 256, 0, stream>>>(ao, wwo, nullptr, nullptr, nullptr, nullptr,
                                                (float*)d_out, wob);
}

// Round 2
// 184.959 us; speedup vs baseline: 1.2130x; 1.2130x over previous
//
#include <hip/hip_runtime.h>
#include <hip/hip_bf16.h>

typedef __attribute__((ext_vector_type(8))) short s16x8;
typedef __attribute__((ext_vector_type(4))) short s16x4;
typedef __attribute__((ext_vector_type(4))) float f32x4;

#define SEQ 2048
#define NB 2
#define NH 16
#define HD 64
#define DIM 1024
#define MR (NB * SEQ)

__device__ __forceinline__ unsigned short f2b(float f) {
    unsigned u = __float_as_uint(f);
    u += 0x7fffu + ((u >> 16) & 1u);
    return (unsigned short)(u >> 16);
}

__device__ __forceinline__ unsigned pk2(float a, float b) {
    __hip_bfloat162 h = __float22bfloat162_rn(float2{a, b}); // v_cvt_pk_bf16_f32
    union { __hip_bfloat162 h; unsigned u; } c; c.h = h;
    return c.u;
}

__device__ __forceinline__ s16x4 mk4(unsigned u0, unsigned u1) {
    union { unsigned u[2]; s16x4 v; } x;
    x.u[0] = u0; x.u[1] = u1;
    return x.v;
}

__device__ __forceinline__ void cast4(const float* __restrict__ src, unsigned short* __restrict__ dst, int i) {
    float4 v = reinterpret_cast<const float4*>(src)[i];
    ushort4 o;
    o.x = f2b(v.x); o.y = f2b(v.y); o.z = f2b(v.z); o.w = f2b(v.w);
    reinterpret_cast<ushort4*>(dst)[i] = o;
}

// One fused prep kernel: casts x,wq,wk,wv,wo to bf16 + builds RoPE cos/sin table.
__global__ __launch_bounds__(256) void prep_kernel(
    const float* __restrict__ x, const float* __restrict__ wq, const float* __restrict__ wk,
    const float* __restrict__ wv, const float* __restrict__ wo,
    unsigned short* __restrict__ xb, unsigned short* __restrict__ wqkv,
    unsigned short* __restrict__ wwo, float2* __restrict__ tab)
{
    int b = blockIdx.x, t = threadIdx.x;
    if (b < 4096)       cast4(x,  xb,                 b * 256 + t);
    else if (b < 5120)  cast4(wq, wqkv,               (b - 4096) * 256 + t);
    else if (b < 6144)  cast4(wk, wqkv + DIM * DIM,   (b - 5120) * 256 + t);
    else if (b < 7168)  cast4(wv, wqkv + 2 * DIM * DIM, (b - 6144) * 256 + t);
    else if (b < 8192)  cast4(wo, wwo,                (b - 7168) * 256 + t);
    else {
        int i = (b - 8192) * 256 + t; // 2048*32 = 65536
        int pos = i >> 5, fi = i & 31;
        float freq = expf((float)fi * (-9.210340371976184f / 32.0f)); // 10000^(-fi/32)
        float emb = (float)pos * freq;
        tab[i] = make_float2(cosf(emb), sinf(emb));
    }
}

// C = A * B^T ; A [M][1024] bf16 row-major, Bw [N][1024] bf16 row-major.
// EPI==0: N=3072 fused QKV; epilogue applies RoPE to Q,K; V stored transposed.
// EPI==1: N=1024 output projection; epilogue adds bias, stores fp32.
template <int EPI>
__global__ __launch_bounds__(256) void gemm_bt(
    const unsigned short* __restrict__ A,
    const unsigned short* __restrict__ Bw,
    const float2* __restrict__ tab,
    unsigned short* __restrict__ qw,
    unsigned short* __restrict__ kw,
    unsigned short* __restrict__ vw,
    float* __restrict__ out,
    const float* __restrict__ bias)
{
    __shared__ unsigned short As[128][40]; // BK=32 + pad 8
    __shared__ unsigned short Bs[128][40];
    const int t = threadIdx.x;
    const int wid = t >> 6;
    const int lane = t & 63;
    const int wr = wid >> 1, wc = wid & 1;
    const int lo = lane & 15, hi = lane >> 4;
    const int m0 = blockIdx.y * 128, n0 = blockIdx.x * 128;
    const int srow = t >> 2, sk = (t & 3) * 8;

    f32x4 acc[4][4] = {};
    const unsigned short* ap0 = A + (long)(m0 + srow) * DIM + sk;
    const unsigned short* ap1 = A + (long)(m0 + srow + 64) * DIM + sk;
    const unsigned short* bp0 = Bw + (long)(n0 + srow) * DIM + sk;
    const unsigned short* bp1 = Bw + (long)(n0 + srow + 64) * DIM + sk;

    for (int k0 = 0; k0 < DIM; k0 += 32) {
        int4 a0 = *reinterpret_cast<const int4*>(ap0 + k0);
        int4 a1 = *reinterpret_cast<const int4*>(ap1 + k0);
        int4 b0 = *reinterpret_cast<const int4*>(bp0 + k0);
        int4 b1 = *reinterpret_cast<const int4*>(bp1 + k0);
        __syncthreads();
        *reinterpret_cast<int4*>(&As[srow][sk]) = a0;
        *reinterpret_cast<int4*>(&As[srow + 64][sk]) = a1;
        *reinterpret_cast<int4*>(&Bs[srow][sk]) = b0;
        *reinterpret_cast<int4*>(&Bs[srow + 64][sk]) = b1;
        __syncthreads();
        s16x8 af[4], bf[4];
#pragma unroll
        for (int i = 0; i < 4; ++i)
            af[i] = *reinterpret_cast<const s16x8*>(&As[wr * 64 + i * 16 + lo][hi * 8]);
#pragma unroll
        for (int j = 0; j < 4; ++j)
            bf[j] = *reinterpret_cast<const s16x8*>(&Bs[wc * 64 + j * 16 + lo][hi * 8]);
#pragma unroll
        for (int i = 0; i < 4; ++i)
#pragma unroll
            for (int j = 0; j < 4; ++j)
                acc[i][j] = __builtin_amdgcn_mfma_f32_16x16x32_bf16(af[i], bf[j], acc[i][j], 0, 0, 0);
    }

    const int rowb = m0 + wr * 64;
    const int colb = n0 + wc * 64;
    if (EPI == 0) {
#pragma unroll
        for (int ai = 0; ai < 4; ++ai) {
#pragma unroll
            for (int cp = 0; cp < 2; ++cp) {
                f32x4 v1 = acc[ai][cp];      // d in [0,32)
                f32x4 v2 = acc[ai][cp + 2];  // d+32
                int e = colb + cp * 16 + lo; // 0..3071
                int which = e >> 10;         // 0=Q 1=K 2=V
                int eh = e & 1023;
                int h = eh >> 6, d = eh & 63;
#pragma unroll
                for (int r = 0; r < 4; ++r) {
                    int m = rowb + ai * 16 + hi * 4 + r;
                    int b = m >> 11, pos = m & (SEQ - 1);
                    long hb = (long)(b * NH + h);
                    if (which == 2) {
                        vw[(hb * HD + d) * SEQ + pos] = f2b(v1[r]);
                        vw[(hb * HD + d + 32) * SEQ + pos] = f2b(v2[r]);
                    } else {
                        float2 cs = tab[pos * 32 + d];
                        unsigned short* dst = (which == 0) ? qw : kw;
                        long off = (hb * SEQ + pos) * HD;
                        dst[off + d]      = f2b(v1[r] * cs.x - v2[r] * cs.y);
                        dst[off + d + 32] = f2b(v1[r] * cs.y + v2[r] * cs.x);
                    }
                }
            }
        }
    } else {
#pragma unroll
        for (int ai = 0; ai < 4; ++ai)
#pragma unroll
            for (int cj = 0; cj < 4; ++cj) {
                int n = colb + cj * 16 + lo;
                float bv = bias[n];
#pragma unroll
                for (int r = 0; r < 4; ++r) {
                    int m = rowb + ai * 16 + hi * 4 + r;
                    out[(long)m * DIM + n] = acc[ai][cj][r] + bv;
                }
            }
    }
}

// Flash attention, swapped-QK^T in-register softmax.
// Grid: (SEQ/64, NB*NH), 4 waves. Wave w owns q columns q0+w*16+lo.
// sc = mfma(K_frag, Q_frag): lane (lo,hi) holds S[k=cj*16+hi*4+r][q=q0w+lo].
// Softmax per lane over its 16 regs + shfl_xor(16,32). P stays in registers:
// its layout IS the A-fragment of mfma_f32_16x16x16bf16_1k (k = hi*4+j).
__global__ __launch_bounds__(256) void flash_attn(
    const unsigned short* __restrict__ qw,
    const unsigned short* __restrict__ kw,
    const unsigned short* __restrict__ vw,
    unsigned short* __restrict__ ao)
{
    __shared__ unsigned short Ks[64][72];
    __shared__ unsigned short Vs[64][72]; // Vs[d][k_local]
    const int t = threadIdx.x;
    const int wid = t >> 6, lane = t & 63;
    const int lo = lane & 15, hi = lane >> 4;
    const int bh = blockIdx.y;
    const int q0 = blockIdx.x * 64;
    const unsigned short* qh = qw + (long)bh * SEQ * HD;
    const unsigned short* kh = kw + (long)bh * SEQ * HD;
    const unsigned short* vh = vw + (long)bh * HD * SEQ;

    // Q fragments straight from global (one row per lane-group, read once)
    s16x8 qf[2];
    {
        const unsigned short* qp = qh + (long)(q0 + wid * 16 + lo) * HD + hi * 8;
        qf[0] = *reinterpret_cast<const s16x8*>(qp);
        qf[1] = *reinterpret_cast<const s16x8*>(qp + 32);
    }

    f32x4 od[4] = {};
    float mrun = -3e38f, lrun = 0.f;
    const float cs = 0.125f * 1.44269504088896340736f; // scale * log2(e)

    const int srow = t >> 3, seg = (t & 7) * 8;

    for (int kt = 0; kt < SEQ / 64; ++kt) {
        const int kb = kt * 64;
        int4 k0v = *reinterpret_cast<const int4*>(kh + (long)(kb + srow) * HD + seg);
        int4 k1v = *reinterpret_cast<const int4*>(kh + (long)(kb + srow + 32) * HD + seg);
        int4 v0v = *reinterpret_cast<const int4*>(vh + (long)srow * SEQ + kb + seg);
        int4 v1v = *reinterpret_cast<const int4*>(vh + (long)(srow + 32) * SEQ + kb + seg);
        __syncthreads();
        *reinterpret_cast<int4*>(&Ks[srow][seg]) = k0v;
        *reinterpret_cast<int4*>(&Ks[srow + 32][seg]) = k1v;
        *reinterpret_cast<int4*>(&Vs[srow][seg]) = v0v;
        *reinterpret_cast<int4*>(&Vs[srow + 32][seg]) = v1v;
        __syncthreads();

        // S^T = K Q^T
        f32x4 sc[4] = {};
        __builtin_amdgcn_s_setprio(1);
#pragma unroll
        for (int ds = 0; ds < 2; ++ds)
#pragma unroll
            for (int cj = 0; cj < 4; ++cj) {
                s16x8 kf = *reinterpret_cast<const s16x8*>(&Ks[cj * 16 + lo][ds * 32 + hi * 8]);
                sc[cj] = __builtin_amdgcn_mfma_f32_16x16x32_bf16(kf, qf[ds], sc[cj], 0, 0, 0);
            }
        __builtin_amdgcn_s_setprio(0);

        // in-register softmax for q = q0w + lo
        float mx = sc[0][0];
#pragma unroll
        for (int cj = 0; cj < 4; ++cj)
#pragma unroll
            for (int r = 0; r < 4; ++r) mx = fmaxf(mx, sc[cj][r]);
        mx = fmaxf(mx, __shfl_xor(mx, 16));
        mx = fmaxf(mx, __shfl_xor(mx, 32));
        if (__any(mx > mrun)) { // defer-max: skip rescale when no lane grew
            float mn = fmaxf(mrun, mx);
            float al = exp2f(cs * (mrun - mn));
            mrun = mn;
            lrun *= al;
#pragma unroll
            for (int r = 0; r < 4; ++r) {
                float ab = __shfl(al, hi * 4 + r); // al for q-local = hi*4+r
#pragma unroll
                for (int cjd = 0; cjd < 4; ++cjd) od[cjd][r] *= ab;
            }
        }
        float cm = cs * mrun;
        float rs = 0.f;
#pragma unroll
        for (int cj = 0; cj < 4; ++cj)
#pragma unroll
            for (int r = 0; r < 4; ++r) {
                float p = exp2f(fmaf(cs, sc[cj][r], -cm));
                sc[cj][r] = p;
                rs += p;
            }
        rs += __shfl_xor(rs, 16);
        rs += __shfl_xor(rs, 32);
        lrun += rs;

        // O += P*V : P already in A-frag layout for 16x16x16 (k = hi*4+j)
        __builtin_amdgcn_s_setprio(1);
#pragma unroll
        for (int cj = 0; cj < 4; ++cj) {
            s16x4 af = mk4(pk2(sc[cj][0], sc[cj][1]), pk2(sc[cj][2], sc[cj][3]));
#pragma unroll
            for (int cjd = 0; cjd < 4; ++cjd) {
                s16x4 bf = *reinterpret_cast<const s16x4*>(&Vs[cjd * 16 + lo][cj * 16 + hi * 4]);
                od[cjd] = __builtin_amdgcn_mfma_f32_16x16x16bf16_1k(af, bf, od[cjd], 0, 0, 0);
            }
        }
        __builtin_amdgcn_s_setprio(0);
    }

    const int b = bh >> 4, h = bh & 15;
    float ool = 1.f / lrun;
#pragma unroll
    for (int r = 0; r < 4; ++r) {
        float ob = __shfl(ool, hi * 4 + r);
        int sr = q0 + wid * 16 + hi * 4 + r;
#pragma unroll
        for (int cjd = 0; cjd < 4; ++cjd) {
            int col = h * 64 + cjd * 16 + lo;
            ao[((long)(b * SEQ + sr)) * DIM + col] = f2b(od[cjd][r] * ob);
        }
    }
}

extern "C" void kernel_launch(void* const* d_in, const int* in_sizes, int n_in,
                              void* d_out, int out_size, void* d_ws, size_t ws_size,
                              hipStream_t stream) {
    const float* x   = (const float*)d_in[0];
    const float* wq  = (const float*)d_in[1];
    const float* wk  = (const float*)d_in[2];
    const float* wv  = (const float*)d_in[3];
    const float* wo  = (const float*)d_in[4];
    const float* wob = (const float*)d_in[5];

    char* ws = (char*)d_ws;
    unsigned short* xb   = (unsigned short*)(ws);             // 8.0 MiB
    unsigned short* wqkv = (unsigned short*)(ws + 8388608);   // 6.0 MiB
    unsigned short* wwo  = (unsigned short*)(ws + 14680064);  // 2.0 MiB
    unsigned short* qw   = (unsigned short*)(ws + 16777216);  // 8.0 MiB
    unsigned short* kw   = (unsigned short*)(ws + 25165824);  // 8.0 MiB
    unsigned short* vw   = (unsigned short*)(ws + 33554432);  // 8.0 MiB
    unsigned short* ao   = (unsigned short*)(ws + 41943040);  // 8.0 MiB
    float2* tab          = (float2*)(ws + 50331648);          // 512 KiB

    prep_kernel<<<8448, 256, 0, stream>>>(x, wq, wk, wv, wo, xb, wqkv, wwo, tab);

    gemm_bt<0><<<dim3(24, 32), 256, 0, stream>>>(xb, wqkv, tab, qw, kw, vw, nullptr, nullptr);
    flash_attn<<<dim3(32, 32), 256, 0, stream>>>(qw, kw, vw, ao);
    gemm_bt<1><<<dim3(8, 32), 256, 0, stream>>>(ao, wwo, nullptr, nullptr, nullptr, nullptr,
                                                (float*)d_out, wob);
}

// Round 3
// 180.690 us; speedup vs baseline: 1.2417x; 1.0236x over previous
//
#include <hip/hip_runtime.h>
#include <hip/hip_bf16.h>

typedef __attribute__((ext_vector_type(8))) short s16x8;
typedef __attribute__((ext_vector_type(4))) short s16x4;
typedef __attribute__((ext_vector_type(4))) float f32x4;

#define SEQ 2048
#define NB 2
#define NH 16
#define HD 64
#define DIM 1024
#define MR (NB * SEQ)

__device__ __forceinline__ unsigned short f2b(float f) {
    unsigned u = __float_as_uint(f);
    u += 0x7fffu + ((u >> 16) & 1u);
    return (unsigned short)(u >> 16);
}

__device__ __forceinline__ unsigned pk2(float a, float b) {
    __hip_bfloat162 h = __float22bfloat162_rn(float2{a, b}); // v_cvt_pk_bf16_f32
    union { __hip_bfloat162 h; unsigned u; } c; c.h = h;
    return c.u;
}

__device__ __forceinline__ s16x4 mk4(unsigned u0, unsigned u1) {
    union { unsigned u[2]; s16x4 v; } x;
    x.u[0] = u0; x.u[1] = u1;
    return x.v;
}

__device__ __forceinline__ void cast4(const float* __restrict__ src, unsigned short* __restrict__ dst, int i) {
    float4 v = reinterpret_cast<const float4*>(src)[i];
    ushort4 o;
    o.x = f2b(v.x); o.y = f2b(v.y); o.z = f2b(v.z); o.w = f2b(v.w);
    reinterpret_cast<ushort4*>(dst)[i] = o;
}

// One fused prep kernel: casts x,wq,wk,wv,wo to bf16 + builds RoPE cos/sin table.
__global__ __launch_bounds__(256) void prep_kernel(
    const float* __restrict__ x, const float* __restrict__ wq, const float* __restrict__ wk,
    const float* __restrict__ wv, const float* __restrict__ wo,
    unsigned short* __restrict__ xb, unsigned short* __restrict__ wqkv,
    unsigned short* __restrict__ wwo, float2* __restrict__ tab)
{
    int b = blockIdx.x, t = threadIdx.x;
    if (b < 4096)       cast4(x,  xb,                 b * 256 + t);
    else if (b < 5120)  cast4(wq, wqkv,               (b - 4096) * 256 + t);
    else if (b < 6144)  cast4(wk, wqkv + DIM * DIM,   (b - 5120) * 256 + t);
    else if (b < 7168)  cast4(wv, wqkv + 2 * DIM * DIM, (b - 6144) * 256 + t);
    else if (b < 8192)  cast4(wo, wwo,                (b - 7168) * 256 + t);
    else {
        int i = (b - 8192) * 256 + t; // 2048*32 = 65536
        int pos = i >> 5, fi = i & 31;
        float freq = expf((float)fi * (-9.210340371976184f / 32.0f)); // 10000^(-fi/32)
        float emb = (float)pos * freq;
        tab[i] = make_float2(cosf(emb), sinf(emb));
    }
}

// C = A * B^T ; A [M][1024] bf16 row-major, Bw [N][1024] bf16 row-major.
// EPI==0: N=3072 fused QKV; epilogue applies RoPE to Q,K; V stored transposed.
// EPI==1: N=1024 output projection; epilogue adds bias, stores fp32.
template <int EPI>
__global__ __launch_bounds__(256) void gemm_bt(
    const unsigned short* __restrict__ A,
    const unsigned short* __restrict__ Bw,
    const float2* __restrict__ tab,
    unsigned short* __restrict__ qw,
    unsigned short* __restrict__ kw,
    unsigned short* __restrict__ vw,
    float* __restrict__ out,
    const float* __restrict__ bias)
{
    __shared__ unsigned short As[128][40]; // BK=32 + pad 8
    __shared__ unsigned short Bs[128][40];
    const int t = threadIdx.x;
    const int wid = t >> 6;
    const int lane = t & 63;
    const int wr = wid >> 1, wc = wid & 1;
    const int lo = lane & 15, hi = lane >> 4;
    const int m0 = blockIdx.y * 128, n0 = blockIdx.x * 128;
    const int srow = t >> 2, sk = (t & 3) * 8;

    f32x4 acc[4][4] = {};
    const unsigned short* ap0 = A + (long)(m0 + srow) * DIM + sk;
    const unsigned short* ap1 = A + (long)(m0 + srow + 64) * DIM + sk;
    const unsigned short* bp0 = Bw + (long)(n0 + srow) * DIM + sk;
    const unsigned short* bp1 = Bw + (long)(n0 + srow + 64) * DIM + sk;

    for (int k0 = 0; k0 < DIM; k0 += 32) {
        int4 a0 = *reinterpret_cast<const int4*>(ap0 + k0);
        int4 a1 = *reinterpret_cast<const int4*>(ap1 + k0);
        int4 b0 = *reinterpret_cast<const int4*>(bp0 + k0);
        int4 b1 = *reinterpret_cast<const int4*>(bp1 + k0);
        __syncthreads();
        *reinterpret_cast<int4*>(&As[srow][sk]) = a0;
        *reinterpret_cast<int4*>(&As[srow + 64][sk]) = a1;
        *reinterpret_cast<int4*>(&Bs[srow][sk]) = b0;
        *reinterpret_cast<int4*>(&Bs[srow + 64][sk]) = b1;
        __syncthreads();
        s16x8 af[4], bf[4];
#pragma unroll
        for (int i = 0; i < 4; ++i)
            af[i] = *reinterpret_cast<const s16x8*>(&As[wr * 64 + i * 16 + lo][hi * 8]);
#pragma unroll
        for (int j = 0; j < 4; ++j)
            bf[j] = *reinterpret_cast<const s16x8*>(&Bs[wc * 64 + j * 16 + lo][hi * 8]);
#pragma unroll
        for (int i = 0; i < 4; ++i)
#pragma unroll
            for (int j = 0; j < 4; ++j)
                acc[i][j] = __builtin_amdgcn_mfma_f32_16x16x32_bf16(af[i], bf[j], acc[i][j], 0, 0, 0);
    }

    const int rowb = m0 + wr * 64;
    const int colb = n0 + wc * 64;
    if (EPI == 0) {
#pragma unroll
        for (int ai = 0; ai < 4; ++ai) {
#pragma unroll
            for (int cp = 0; cp < 2; ++cp) {
                f32x4 v1 = acc[ai][cp];      // d in [0,32)
                f32x4 v2 = acc[ai][cp + 2];  // d+32
                int e = colb + cp * 16 + lo; // 0..3071
                int which = e >> 10;         // 0=Q 1=K 2=V
                int eh = e & 1023;
                int h = eh >> 6, d = eh & 63;
#pragma unroll
                for (int r = 0; r < 4; ++r) {
                    int m = rowb + ai * 16 + hi * 4 + r;
                    int b = m >> 11, pos = m & (SEQ - 1);
                    long hb = (long)(b * NH + h);
                    if (which == 2) {
                        vw[(hb * HD + d) * SEQ + pos] = f2b(v1[r]);
                        vw[(hb * HD + d + 32) * SEQ + pos] = f2b(v2[r]);
                    } else {
                        float2 cs = tab[pos * 32 + d];
                        unsigned short* dst = (which == 0) ? qw : kw;
                        long off = (hb * SEQ + pos) * HD;
                        dst[off + d]      = f2b(v1[r] * cs.x - v2[r] * cs.y);
                        dst[off + d + 32] = f2b(v1[r] * cs.y + v2[r] * cs.x);
                    }
                }
            }
        }
    } else {
#pragma unroll
        for (int ai = 0; ai < 4; ++ai)
#pragma unroll
            for (int cj = 0; cj < 4; ++cj) {
                int n = colb + cj * 16 + lo;
                float bv = bias[n];
#pragma unroll
                for (int r = 0; r < 4; ++r) {
                    int m = rowb + ai * 16 + hi * 4 + r;
                    out[(long)m * DIM + n] = acc[ai][cj][r] + bv;
                }
            }
    }
}

// Flash attention, swapped-QK^T in-register softmax, double-buffered LDS,
// one barrier per tile, speculative exp (defer-max THR=8), per-lane lrun.
// Grid: (SEQ/64, NB*NH), 4 waves. Wave w owns q columns q0+w*16+lo.
__global__ __launch_bounds__(256) void flash_attn(
    const unsigned short* __restrict__ qw,
    const unsigned short* __restrict__ kw,
    const unsigned short* __restrict__ vw,
    unsigned short* __restrict__ ao)
{
    __shared__ unsigned short Ks[2][64][72];
    __shared__ unsigned short Vs[2][64][72]; // Vs[buf][d][k_local]
    const int t = threadIdx.x;
    const int wid = t >> 6, lane = t & 63;
    const int lo = lane & 15, hi = lane >> 4;
    const int bh = blockIdx.y;
    const int q0 = blockIdx.x * 64;
    const unsigned short* qh = qw + (long)bh * SEQ * HD;
    const unsigned short* kh = kw + (long)bh * SEQ * HD;
    const unsigned short* vh = vw + (long)bh * HD * SEQ;

    // Q fragments straight from global (read once)
    s16x8 qf[2];
    {
        const unsigned short* qp = qh + (long)(q0 + wid * 16 + lo) * HD + hi * 8;
        qf[0] = *reinterpret_cast<const s16x8*>(qp);
        qf[1] = *reinterpret_cast<const s16x8*>(qp + 32);
    }

    f32x4 od[4] = {};
    float mrun = -3.0e38f, lrun = 0.f;
    const float cs = 0.125f * 1.44269504088896340736f; // scale * log2(e)

    const int srow = t >> 3, seg = (t & 7) * 8;

    int4 k0v, k1v, v0v, v1v; // staging registers (async-stage split)
#define LOADT(kb)                                                                        \
    {                                                                                    \
        k0v = *reinterpret_cast<const int4*>(kh + (long)((kb) + srow) * HD + seg);       \
        k1v = *reinterpret_cast<const int4*>(kh + (long)((kb) + srow + 32) * HD + seg);  \
        v0v = *reinterpret_cast<const int4*>(vh + (long)srow * SEQ + (kb) + seg);        \
        v1v = *reinterpret_cast<const int4*>(vh + (long)(srow + 32) * SEQ + (kb) + seg); \
    }
#define STORET(c)                                                  \
    {                                                              \
        *reinterpret_cast<int4*>(&Ks[c][srow][seg]) = k0v;         \
        *reinterpret_cast<int4*>(&Ks[c][srow + 32][seg]) = k1v;    \
        *reinterpret_cast<int4*>(&Vs[c][srow][seg]) = v0v;         \
        *reinterpret_cast<int4*>(&Vs[c][srow + 32][seg]) = v1v;    \
    }

    LOADT(0);
    STORET(0);
    int cb = 0;

    for (int kt = 0; kt < SEQ / 64; ++kt) {
        __syncthreads(); // buf cb ready; everyone done reading cb^1 (tile kt-1)
        if (kt + 1 < SEQ / 64) LOADT((kt + 1) * 64); // in flight across compute

        // S^T = K Q^T from Ks[cb]
        f32x4 sc[4] = {};
        __builtin_amdgcn_s_setprio(1);
#pragma unroll
        for (int ds = 0; ds < 2; ++ds)
#pragma unroll
            for (int cj = 0; cj < 4; ++cj) {
                s16x8 kf = *reinterpret_cast<const s16x8*>(&Ks[cb][cj * 16 + lo][ds * 32 + hi * 8]);
                sc[cj] = __builtin_amdgcn_mfma_f32_16x16x32_bf16(kf, qf[ds], sc[cj], 0, 0, 0);
            }
        __builtin_amdgcn_s_setprio(0);

        // speculative exp with OLD running max (off the fmax/shfl critical path)
        float cm = cs * mrun;
        f32x4 pr[4];
#pragma unroll
        for (int cj = 0; cj < 4; ++cj)
#pragma unroll
            for (int r = 0; r < 4; ++r)
                pr[cj][r] = exp2f(fmaf(cs, sc[cj][r], -cm));

        // parallel: tile max + check
        float mx = sc[0][0];
#pragma unroll
        for (int cj = 0; cj < 4; ++cj)
#pragma unroll
            for (int r = 0; r < 4; ++r) mx = fmaxf(mx, sc[cj][r]);
        mx = fmaxf(mx, __shfl_xor(mx, 16));
        mx = fmaxf(mx, __shfl_xor(mx, 32));

        if (__any(mx > mrun + 8.0f)) { // rare after early tiles
            float mn = fmaxf(mrun, mx);
            float al = exp2f(cs * (mrun - mn));
            mrun = mn;
            cm = cs * mrun;
            lrun *= al;
#pragma unroll
            for (int r = 0; r < 4; ++r) {
                float ab = __shfl(al, hi * 4 + r);
#pragma unroll
                for (int cjd = 0; cjd < 4; ++cjd) od[cjd][r] *= ab;
            }
#pragma unroll
            for (int cj = 0; cj < 4; ++cj)
#pragma unroll
                for (int r = 0; r < 4; ++r)
                    pr[cj][r] = exp2f(fmaf(cs, sc[cj][r], -cm));
        }

        // per-lane partial row-sum (cross-lane reduce deferred to epilogue)
        float rs = 0.f;
#pragma unroll
        for (int cj = 0; cj < 4; ++cj)
#pragma unroll
            for (int r = 0; r < 4; ++r) rs += pr[cj][r];
        lrun += rs;

        // O += P*V : P in A-frag layout for 16x16x16 (k = hi*4+j)
        __builtin_amdgcn_s_setprio(1);
#pragma unroll
        for (int cj = 0; cj < 4; ++cj) {
            s16x4 af = mk4(pk2(pr[cj][0], pr[cj][1]), pk2(pr[cj][2], pr[cj][3]));
#pragma unroll
            for (int cjd = 0; cjd < 4; ++cjd) {
                s16x4 bf = *reinterpret_cast<const s16x4*>(&Vs[cb][cjd * 16 + lo][cj * 16 + hi * 4]);
                od[cjd] = __builtin_amdgcn_mfma_f32_16x16x16bf16_1k(af, bf, od[cjd], 0, 0, 0);
            }
        }
        __builtin_amdgcn_s_setprio(0);

        if (kt + 1 < SEQ / 64) {
            STORET(cb ^ 1); // waits vmcnt internally; safe: cb^1 readers passed top barrier
            cb ^= 1;
        }
    }

    // final cross-lane l reduction (once, not per tile)
    lrun += __shfl_xor(lrun, 16);
    lrun += __shfl_xor(lrun, 32);

    const int b = bh >> 4, h = bh & 15;
    float ool = 1.f / lrun;
#pragma unroll
    for (int r = 0; r < 4; ++r) {
        float ob = __shfl(ool, hi * 4 + r);
        int sr = q0 + wid * 16 + hi * 4 + r;
#pragma unroll
        for (int cjd = 0; cjd < 4; ++cjd) {
            int col = h * 64 + cjd * 16 + lo;
            ao[((long)(b * SEQ + sr)) * DIM + col] = f2b(od[cjd][r] * ob);
        }
    }
#undef LOADT
#undef STORET
}

extern "C" void kernel_launch(void* const* d_in, const int* in_sizes, int n_in,
                              void* d_out, int out_size, void* d_ws, size_t ws_size,
                              hipStream_t stream) {
    const float* x   = (const float*)d_in[0];
    const float* wq  = (const float*)d_in[1];
    const float* wk  = (const float*)d_in[2];
    const float* wv  = (const float*)d_in[3];
    const float* wo  = (const float*)d_in[4];
    const float* wob = (const float*)d_in[5];

    char* ws = (char*)d_ws;
    unsigned short* xb   = (unsigned short*)(ws);             // 8.0 MiB
    unsigned short* wqkv = (unsigned short*)(ws + 8388608);   // 6.0 MiB
    unsigned short* wwo  = (unsigned short*)(ws + 14680064);  // 2.0 MiB
    unsigned short* qw   = (unsigned short*)(ws + 16777216);  // 8.0 MiB
    unsigned short* kw   = (unsigned short*)(ws + 25165824);  // 8.0 MiB
    unsigned short* vw   = (unsigned short*)(ws + 33554432);  // 8.0 MiB
    unsigned short* ao   = (unsigned short*)(ws + 41943040);  // 8.0 MiB
    float2* tab          = (float2*)(ws + 50331648);          // 512 KiB

    prep_kernel<<<8448, 256, 0, stream>>>(x, wq, wk, wv, wo, xb, wqkv, wwo, tab);

    gemm_bt<0><<<dim3(24, 32), 256, 0, stream>>>(xb, wqkv, tab, qw, kw, vw, nullptr, nullptr);
    flash_attn<<<dim3(32, 32), 256, 0, stream>>>(qw, kw, vw, ao);
    gemm_bt<1><<<dim3(8, 32), 256, 0, stream>>>(ao, wwo, nullptr, nullptr, nullptr, nullptr,
                                                (float*)d_out, wob);
}